// Round 2
// baseline (1245.617 us; speedup 1.0000x reference)
//
#include <hip/hip_runtime.h>
#include <cstdint>

// DynamicConv on MI355X — round 2: fp32 baseline, improved conv instruction mix.
// B=32, C1=C2=128, K_EXP=4, KS=3, H=W=96, TEMP=1, EPS=1e-5.
//
// Pipeline:
//   k_gap    : per-(b,c1) mean over 96x96            -> ws.gap
//   k_gate   : logits+softmax (32x4), bmix (32x128)  -> ws.gate, ws.bmix
//   k_wmixT  : per-sample mixed 3x3 kernels, layout  -> ws.wmixT [b][c1][9][c2]
//              (transposed so conv weight loads are lane-coalesced; also the
//               right B-operand layout for a future MFMA implicit GEMM)
//   k_conv   : per-sample 3x3 conv, y -> d_out. lane=c2, 48 cols/thread,
//              x rows via float4, weights via coalesced dword loads. No LDS.
//   k_bnstat : per-channel partial sum/sumsq over (B,H,W)
//   k_bnfinal: mean/var -> scale/shift per c2
//   k_silu   : in-place y = silu(y*scale+shift) on d_out

#define B_    32
#define C1_   128
#define C2_   128
#define KEXP_ 4
#define H_    96
#define W_    96
#define HW_   (H_ * W_)
#define EPS_  1e-5f

// ws layout in floats:
#define WS_GAP   0          // [32][128]             4096
#define WS_GATE  4096       // [32][4]               128
#define WS_BMIX  4224       // [32][128]             4096
#define WS_PSUM  8320       // [128][8]              1024
#define WS_PSQ   9344       // [128][8]              1024
#define WS_SCALE 10368      // [128]                 128
#define WS_SHIFT 10496      // [128]                 128
#define WS_WMIX  10624      // [32][128][9][128]     4718592 (byte ofs 42496, 16B aligned)

__device__ inline float wave_reduce_sum(float v) {
#pragma unroll
    for (int o = 32; o > 0; o >>= 1) v += __shfl_down(v, o, 64);
    return v;
}

// ---------------- GAP: mean over HxW per (b,c1) ----------------
__global__ __launch_bounds__(256) void k_gap(const float* __restrict__ x,
                                             float* __restrict__ gap) {
    const int c1 = blockIdx.x, b = blockIdx.y, t = threadIdx.x;
    const float4* p = (const float4*)(x + ((size_t)(b * C1_ + c1)) * HW_);
    float s = 0.f;
#pragma unroll
    for (int i = 0; i < 9; ++i) {            // 2304 float4 = 9 * 256 exactly
        float4 v = p[t + i * 256];
        s += v.x + v.y + v.z + v.w;
    }
    s = wave_reduce_sum(s);
    __shared__ float ls[4];
    if ((t & 63) == 0) ls[t >> 6] = s;
    __syncthreads();
    if (t == 0) gap[b * C1_ + c1] = (ls[0] + ls[1] + ls[2] + ls[3]) * (1.f / HW_);
}

// ---------------- gating softmax + bmix ----------------
__global__ __launch_bounds__(128) void k_gate(const float* __restrict__ gap,
                                              const float* __restrict__ fc_w,
                                              const float* __restrict__ fc_b,
                                              const float* __restrict__ bias,
                                              float* __restrict__ gate,
                                              float* __restrict__ bmix) {
    const int t = threadIdx.x;
    if (t < B_) {
        const int b = t;
        float lg[KEXP_];
#pragma unroll
        for (int k = 0; k < KEXP_; ++k) {
            float s = 0.f;
            for (int c = 0; c < C1_; ++c) s += gap[b * C1_ + c] * fc_w[k * C1_ + c];
            lg[k] = s + fc_b[k];             // TEMP = 1
        }
        float m = fmaxf(fmaxf(lg[0], lg[1]), fmaxf(lg[2], lg[3]));
        float e0 = __expf(lg[0] - m), e1 = __expf(lg[1] - m);
        float e2 = __expf(lg[2] - m), e3 = __expf(lg[3] - m);
        float inv = 1.f / (e0 + e1 + e2 + e3);
        gate[b * 4 + 0] = e0 * inv; gate[b * 4 + 1] = e1 * inv;
        gate[b * 4 + 2] = e2 * inv; gate[b * 4 + 3] = e3 * inv;
    }
    __syncthreads();
    const int c2 = t;                        // 128 threads = C2
    for (int b = 0; b < B_; ++b) {
        float s = 0.f;
#pragma unroll
        for (int k = 0; k < KEXP_; ++k) s += gate[b * 4 + k] * bias[k * C2_ + c2];
        bmix[b * C2_ + c2] = s;
    }
}

// ---------------- per-sample mixed kernels, transposed to [b][c1][9][c2] ----
__global__ __launch_bounds__(128) void k_wmixT(const float* __restrict__ weight,
                                               const float* __restrict__ gate,
                                               float* __restrict__ wmixT) {
    const int c2 = threadIdx.x;              // 0..127
    const int c1 = blockIdx.x;               // 0..127
    const int b  = blockIdx.y;               // 0..31
    const float g0 = gate[b * 4 + 0], g1 = gate[b * 4 + 1];
    const float g2 = gate[b * 4 + 2], g3 = gate[b * 4 + 3];
    const int EX = C2_ * C1_ * 9;            // 147456 floats per expert
    const float* w0 = weight + ((size_t)c2 * C1_ + c1) * 9;
    float* o = wmixT + (((size_t)b * C1_ + c1) * 9) * C2_ + c2;
#pragma unroll
    for (int j = 0; j < 9; ++j) {
        float v = g0 * w0[j] + g1 * w0[EX + j] + g2 * w0[2 * EX + j] + g3 * w0[3 * EX + j];
        o[j * C2_] = v;                      // lane-coalesced store
    }
}

// ---------------- the conv ----------------
// Block: (strip 0..1, h 0..95, b 0..31), 128 threads; lane = c2.
// Each thread produces 48 consecutive output columns for one (b,c2,h).
// Per c1: 9 lane-coalesced weight dword loads + per-row 12 float4 + 2 edge
// scalar x loads (wave-uniform addresses). 432 FMAs per c1. No LDS.
__global__ __launch_bounds__(128) void k_conv(const float* __restrict__ x,
                                              const float* __restrict__ wmixT,
                                              const float* __restrict__ bmix,
                                              float* __restrict__ y) {
    const int c2 = threadIdx.x;              // 0..127
    const int cb = blockIdx.x * 48;          // 0 or 48
    const int h  = blockIdx.y;               // 0..95
    const int b  = blockIdx.z;               // 0..31

    const float* xb  = x + ((size_t)b * C1_) * HW_;
    const float* wTb = wmixT + (size_t)b * (C1_ * 9 * C2_) + c2;

    float acc[48];
    const float binit = bmix[b * C2_ + c2];
#pragma unroll
    for (int p = 0; p < 48; ++p) acc[p] = binit;

    for (int c1 = 0; c1 < C1_; ++c1) {
        float wr[9];
#pragma unroll
        for (int j = 0; j < 9; ++j) wr[j] = wTb[(c1 * 9 + j) * C2_];

        const float* xc = xb + c1 * HW_;
#pragma unroll
        for (int dy = 0; dy < 3; ++dy) {
            const int hy = h + dy - 1;
            if (hy < 0 || hy >= H_) continue;          // zero row padding
            const float* xrow = xc + hy * W_ + cb;     // float4-aligned
            float sx[50];                              // cols cb-1 .. cb+48
            sx[0] = (cb > 0) ? xrow[-1] : 0.f;         // left pad
            const float4* xr4 = (const float4*)xrow;
#pragma unroll
            for (int i = 0; i < 12; ++i) {
                float4 v = xr4[i];
                sx[1 + 4 * i] = v.x; sx[2 + 4 * i] = v.y;
                sx[3 + 4 * i] = v.z; sx[4 + 4 * i] = v.w;
            }
            sx[49] = (cb + 48 < W_) ? xrow[48] : 0.f;  // right pad
#pragma unroll
            for (int dx = 0; dx < 3; ++dx) {
                const float wv = wr[dy * 3 + dx];
#pragma unroll
                for (int p = 0; p < 48; ++p) acc[p] += sx[p + dx] * wv;
            }
        }
    }
    float* yrow = y + ((size_t)(b * C2_ + c2)) * HW_ + h * W_ + cb;
#pragma unroll
    for (int p = 0; p < 48; ++p) yrow[p] = acc[p];
}

// ---------------- BN partial stats ----------------
__global__ __launch_bounds__(256) void k_bnstat(const float* __restrict__ y,
                                                float* __restrict__ psum,
                                                float* __restrict__ psq) {
    const int c2 = blockIdx.x, s = blockIdx.y, t = threadIdx.x;
    float sum = 0.f, sq = 0.f;
#pragma unroll
    for (int bi = 0; bi < 4; ++bi) {
        const int b = s * 4 + bi;
        const float4* p = (const float4*)(y + ((size_t)(b * C2_ + c2)) * HW_);
#pragma unroll
        for (int i = 0; i < 9; ++i) {
            float4 v = p[t + i * 256];
            sum += v.x + v.y + v.z + v.w;
            sq  += v.x * v.x + v.y * v.y + v.z * v.z + v.w * v.w;
        }
    }
    sum = wave_reduce_sum(sum);
    sq  = wave_reduce_sum(sq);
    __shared__ float ls[2][4];
    if ((t & 63) == 0) { ls[0][t >> 6] = sum; ls[1][t >> 6] = sq; }
    __syncthreads();
    if (t == 0) {
        psum[c2 * 8 + s] = ls[0][0] + ls[0][1] + ls[0][2] + ls[0][3];
        psq [c2 * 8 + s] = ls[1][0] + ls[1][1] + ls[1][2] + ls[1][3];
    }
}

__global__ __launch_bounds__(128) void k_bnfinal(const float* __restrict__ psum,
                                                 const float* __restrict__ psq,
                                                 const float* __restrict__ gamma,
                                                 const float* __restrict__ beta,
                                                 float* __restrict__ scale,
                                                 float* __restrict__ shift) {
    const int c2 = threadIdx.x;
    float s = 0.f, q = 0.f;
#pragma unroll
    for (int i = 0; i < 8; ++i) { s += psum[c2 * 8 + i]; q += psq[c2 * 8 + i]; }
    const float n = (float)(B_ * HW_);
    const float mean = s / n;
    const float var  = q / n - mean * mean;       // population var (ddof=0)
    const float sc   = gamma[c2] * rsqrtf(var + EPS_);
    scale[c2] = sc;
    shift[c2] = beta[c2] - mean * sc;
}

// ---------------- BN apply + SiLU, in place on d_out ----------------
__global__ __launch_bounds__(256) void k_silu(float* __restrict__ y,
                                              const float* __restrict__ scale,
                                              const float* __restrict__ shift) {
    const int bc = blockIdx.y;                // b*128 + c2
    const int c2 = bc & 127;
    const int i  = blockIdx.x * 256 + threadIdx.x;   // 0..2303 (exact)
    const float sc = scale[c2], sh = shift[c2];
    float4* p = (float4*)(y + (size_t)bc * HW_);
    float4 v = p[i];
    float t0 = v.x * sc + sh; v.x = t0 / (1.f + __expf(-t0));
    float t1 = v.y * sc + sh; v.y = t1 / (1.f + __expf(-t1));
    float t2 = v.z * sc + sh; v.z = t2 / (1.f + __expf(-t2));
    float t3 = v.w * sc + sh; v.w = t3 / (1.f + __expf(-t3));
    p[i] = v;
}

extern "C" void kernel_launch(void* const* d_in, const int* in_sizes, int n_in,
                              void* d_out, int out_size, void* d_ws, size_t ws_size,
                              hipStream_t stream) {
    (void)in_sizes; (void)n_in; (void)out_size; (void)ws_size;
    const float* x      = (const float*)d_in[0];
    const float* fc_w   = (const float*)d_in[1];
    const float* fc_b   = (const float*)d_in[2];
    const float* weight = (const float*)d_in[3];
    const float* bias   = (const float*)d_in[4];
    const float* gamma  = (const float*)d_in[5];
    const float* beta   = (const float*)d_in[6];
    float* out = (float*)d_out;
    float* ws  = (float*)d_ws;

    float* gap   = ws + WS_GAP;
    float* gate  = ws + WS_GATE;
    float* bmix  = ws + WS_BMIX;
    float* psum  = ws + WS_PSUM;
    float* psq   = ws + WS_PSQ;
    float* scale = ws + WS_SCALE;
    float* shift = ws + WS_SHIFT;
    float* wmixT = ws + WS_WMIX;

    hipLaunchKernelGGL(k_gap,    dim3(C1_, B_),    dim3(256), 0, stream, x, gap);
    hipLaunchKernelGGL(k_gate,   dim3(1),          dim3(128), 0, stream, gap, fc_w, fc_b, bias, gate, bmix);
    hipLaunchKernelGGL(k_wmixT,  dim3(C1_, B_),    dim3(128), 0, stream, weight, gate, wmixT);
    hipLaunchKernelGGL(k_conv,   dim3(2, H_, B_),  dim3(128), 0, stream, x, wmixT, bmix, out);
    hipLaunchKernelGGL(k_bnstat, dim3(C2_, 8),     dim3(256), 0, stream, out, psum, psq);
    hipLaunchKernelGGL(k_bnfinal,dim3(1),          dim3(128), 0, stream, psum, psq, gamma, beta, scale, shift);
    hipLaunchKernelGGL(k_silu,   dim3(9, B_ * C2_), dim3(256), 0, stream, out, scale, shift);
}

// Round 3
// 982.118 us; speedup vs baseline: 1.2683x; 1.2683x over previous
//
#include <hip/hip_runtime.h>
#include <cstdint>

// DynamicConv on MI355X — round 3: split-bf16 MFMA implicit-GEMM conv.
// B=32, C1=C2=128, KS=3, H=W=96. Conv as 9 shifted K=128 GEMMs per sample,
// fp32 accuracy via (wh+wl)x(xh+xl) with 3 MFMA products (hh, lh, hl).
//
//   memset gap
//   k_xpad  : x -> padded NHWC bf16 hi/lo [b][98][98][128]; fuses GAP sums
//   k_gate  : softmax gate + bmix
//   k_wmixA : mixed weights -> MFMA-fragment-ordered bf16 hi/lo
//   k_conv  : per (b,h-row) block: M=128(c2) x N=96(w), K=9*128.
//             A-frags direct from global (lane-contiguous), B via swizzled LDS.
//   k_bnstat/k_bnfinal/k_silu : unchanged from round 2.
//
// NOTE: requires ws_size >= 176.3 MB (xh+xl 157MB + whf/wlf 18.9MB + small).

#define B_    32
#define C1_   128
#define C2_   128
#define H_    96
#define W_    96
#define HW_   (H_ * W_)
#define HP_   98
#define WP_   98
#define EPS_  1e-5f

typedef __attribute__((ext_vector_type(8))) __bf16 bf16x8;
typedef __attribute__((ext_vector_type(4))) float f32x4;

// ws layout in float slots:
#define WS_GAP   0          // [32][128] (sums, atomically accumulated)
#define WS_GATE  4096
#define WS_BMIX  4224
#define WS_PSUM  8320
#define WS_PSQ   9344
#define WS_SCALE 10368
#define WS_SHIFT 10496
#define WS_WHF   10752                    // ushort[32*9*4*8*64*8] = 4,718,592
#define WS_WLF   (WS_WHF + 2359296)
#define WS_XH    (WS_WLF + 2359296)       // ushort[32*98*98*128] = 39,337,984
#define WS_XL    (WS_XH + 19668992)
// end = WS_XL + 19668992 = 44,067,328 floats = 176.3 MB

__device__ inline float bfbits2f(unsigned short u) {
    return (float)__builtin_bit_cast(__bf16, u);
}

// ---------------- x -> padded NHWC bf16 hi/lo, + GAP sums ----------------
__global__ __launch_bounds__(256) void k_xpad(const float* __restrict__ x,
                                              unsigned short* __restrict__ xh,
                                              unsigned short* __restrict__ xl,
                                              float* __restrict__ gap) {
    __shared__ unsigned int lds[96 * 129];      // [w][c1], pad 129 -> conflict-free
    const int hp = blockIdx.x, b = blockIdx.y, t = threadIdx.x;
    const size_t rowbase = ((size_t)b * HP_ + hp) * WP_ * C1_;
    if (hp == 0 || hp == HP_ - 1) {             // zero pad rows (block-uniform)
        const ushort4 z = {0, 0, 0, 0};
        for (int i = 0; i < 13; ++i) {
            int idx = i * 256 + t;
            if (idx < 3136) {                   // 98*128/4
                *(ushort4*)(xh + rowbase + (size_t)idx * 4) = z;
                *(ushort4*)(xl + rowbase + (size_t)idx * 4) = z;
            }
        }
        return;
    }
    const int h = hp - 1;
    // phase 1: coalesced read of x[b][*][h][*], split to bf16 hi/lo, pack in LDS
    for (int i = 0; i < 48; ++i) {
        int idx = i * 256 + t;                  // 0..12287 = c1*96 + w
        int c1 = idx / 96, w = idx - c1 * 96;
        float v = x[((size_t)(b * C1_ + c1)) * HW_ + h * W_ + w];
        __bf16 hi = (__bf16)v;
        __bf16 lo = (__bf16)(v - (float)hi);
        lds[w * 129 + c1] = (unsigned int)__builtin_bit_cast(unsigned short, hi)
                          | ((unsigned int)__builtin_bit_cast(unsigned short, lo) << 16);
    }
    // w pads for this row
    if (t < 128) { xh[rowbase + t] = 0; xl[rowbase + t] = 0; }
    else {
        int c1 = t - 128;
        xh[rowbase + (size_t)(WP_ - 1) * C1_ + c1] = 0;
        xl[rowbase + (size_t)(WP_ - 1) * C1_ + c1] = 0;
    }
    __syncthreads();
    // phase 2: transposed write (4 c1 per thread -> 8B stores) + GAP partials
    const int c14 = (t & 31) << 2;              // fixed 4 channels per thread
    float s0 = 0, s1 = 0, s2 = 0, s3 = 0;
    for (int i = 0; i < 12; ++i) {
        int quad = i * 256 + t;                 // 0..3071
        int w = quad >> 5;
        unsigned int u0 = lds[w * 129 + c14 + 0];
        unsigned int u1 = lds[w * 129 + c14 + 1];
        unsigned int u2 = lds[w * 129 + c14 + 2];
        unsigned int u3 = lds[w * 129 + c14 + 3];
        ushort4 hv = {(unsigned short)u0, (unsigned short)u1,
                      (unsigned short)u2, (unsigned short)u3};
        ushort4 lv = {(unsigned short)(u0 >> 16), (unsigned short)(u1 >> 16),
                      (unsigned short)(u2 >> 16), (unsigned short)(u3 >> 16)};
        size_t off = rowbase + (size_t)(w + 1) * C1_ + c14;
        *(ushort4*)(xh + off) = hv;
        *(ushort4*)(xl + off) = lv;
        s0 += bfbits2f(hv.x) + bfbits2f(lv.x);
        s1 += bfbits2f(hv.y) + bfbits2f(lv.y);
        s2 += bfbits2f(hv.z) + bfbits2f(lv.z);
        s3 += bfbits2f(hv.w) + bfbits2f(lv.w);
    }
    s0 += __shfl_xor(s0, 32); s1 += __shfl_xor(s1, 32);
    s2 += __shfl_xor(s2, 32); s3 += __shfl_xor(s3, 32);
    if ((t & 63) < 32) {
        atomicAdd(&gap[b * C1_ + c14 + 0], s0);
        atomicAdd(&gap[b * C1_ + c14 + 1], s1);
        atomicAdd(&gap[b * C1_ + c14 + 2], s2);
        atomicAdd(&gap[b * C1_ + c14 + 3], s3);
    }
}

// ---------------- gating softmax + bmix (gap holds SUMS) ----------------
__global__ __launch_bounds__(128) void k_gate(const float* __restrict__ gap,
                                              const float* __restrict__ fc_w,
                                              const float* __restrict__ fc_b,
                                              const float* __restrict__ bias,
                                              float* __restrict__ gate,
                                              float* __restrict__ bmix) {
    const int t = threadIdx.x;
    if (t < B_) {
        const int b = t;
        const float inv = 1.0f / (float)HW_;
        float lg[4];
#pragma unroll
        for (int k = 0; k < 4; ++k) {
            float s = 0.f;
            for (int c = 0; c < C1_; ++c) s += gap[b * C1_ + c] * fc_w[k * C1_ + c];
            lg[k] = s * inv + fc_b[k];
        }
        float m = fmaxf(fmaxf(lg[0], lg[1]), fmaxf(lg[2], lg[3]));
        float e0 = __expf(lg[0] - m), e1 = __expf(lg[1] - m);
        float e2 = __expf(lg[2] - m), e3 = __expf(lg[3] - m);
        float inv2 = 1.f / (e0 + e1 + e2 + e3);
        gate[b * 4 + 0] = e0 * inv2; gate[b * 4 + 1] = e1 * inv2;
        gate[b * 4 + 2] = e2 * inv2; gate[b * 4 + 3] = e3 * inv2;
    }
    __syncthreads();
    const int c2 = t;
    for (int b = 0; b < B_; ++b) {
        float s = 0.f;
#pragma unroll
        for (int k = 0; k < 4; ++k) s += gate[b * 4 + k] * bias[k * C2_ + c2];
        bmix[b * C2_ + c2] = s;
    }
}

// ---------------- mixed weights -> fragment-ordered bf16 hi/lo ----------------
// whf[b][j][c1b][g16][lane][8]: lane=koct*16+l15 -> (c2=g16*16+l15, c1=c1b*32+koct*8+e)
__global__ __launch_bounds__(256) void k_wmixA(const float* __restrict__ weight,
                                               const float* __restrict__ gate,
                                               unsigned short* __restrict__ whf,
                                               unsigned short* __restrict__ wlf) {
    const int jc = blockIdx.x;                  // j*4 + c1b
    const int j = jc >> 2, c1b = jc & 3;
    const int b = blockIdx.y, t = threadIdx.x;
    const int lane = t & 63, quarter = t >> 6;
    const int l15 = lane & 15, koct = lane >> 4;
    const float g0 = gate[b * 4 + 0], g1 = gate[b * 4 + 1];
    const float g2 = gate[b * 4 + 2], g3 = gate[b * 4 + 3];
#pragma unroll
    for (int gg = 0; gg < 2; ++gg) {
        const int g16 = quarter * 2 + gg;
        const int c2 = g16 * 16 + l15;
        unsigned int hw_[4], lw_[4];
#pragma unroll
        for (int ep = 0; ep < 4; ++ep) {
            unsigned short hv[2], lv[2];
#pragma unroll
            for (int s = 0; s < 2; ++s) {
                const int e = ep * 2 + s;
                const int c1 = c1b * 32 + koct * 8 + e;
                const size_t wi = ((size_t)c2 * C1_ + c1) * 9 + j;
                float mix = g0 * weight[wi] + g1 * weight[wi + 147456]
                          + g2 * weight[wi + 2 * 147456] + g3 * weight[wi + 3 * 147456];
                __bf16 hi = (__bf16)mix;
                __bf16 lo = (__bf16)(mix - (float)hi);
                hv[s] = __builtin_bit_cast(unsigned short, hi);
                lv[s] = __builtin_bit_cast(unsigned short, lo);
            }
            hw_[ep] = (unsigned int)hv[0] | ((unsigned int)hv[1] << 16);
            lw_[ep] = (unsigned int)lv[0] | ((unsigned int)lv[1] << 16);
        }
        const size_t base = ((((size_t)(b * 9 + j) * 4 + c1b) * 8 + g16) * 64 + lane) * 8;
        uint4 hu = {hw_[0], hw_[1], hw_[2], hw_[3]};
        uint4 lu = {lw_[0], lw_[1], lw_[2], lw_[3]};
        *(uint4*)(whf + base) = hu;             // lane-contiguous 16B -> coalesced
        *(uint4*)(wlf + base) = lu;
    }
}

// ---------------- MFMA implicit-GEMM conv ----------------
// Block (h, b), 256 thr = 4 waves (2M x 2N). Wave tile M=64 x N=48.
// LDS B-tile per c1-block: [3 rows][98 wp][32 c1] hi+lo, XOR-swizzled 16B slots.
__global__ __launch_bounds__(256) void k_conv(const unsigned short* __restrict__ xh,
                                              const unsigned short* __restrict__ xl,
                                              const unsigned short* __restrict__ whf,
                                              const unsigned short* __restrict__ wlf,
                                              const float* __restrict__ bmix,
                                              float* __restrict__ y) {
    __shared__ unsigned short Bh[3 * 98 * 32];
    __shared__ unsigned short Bl[3 * 98 * 32];
    const int h = blockIdx.x, b = blockIdx.y, t = threadIdx.x;
    const int wv = t >> 6, lane = t & 63;
    const int wm = wv >> 1, wn = wv & 1;
    const int l15 = lane & 15, koct = lane >> 4;
    const size_t xrow0 = ((size_t)b * HP_ + h) * WP_ * (size_t)C1_;

    f32x4 acc[4][3];
#pragma unroll
    for (int m = 0; m < 4; ++m)
#pragma unroll
        for (int n = 0; n < 3; ++n) acc[m][n] = (f32x4){0.f, 0.f, 0.f, 0.f};

    uint4 sreg[10];                             // next-tile staging registers

#define STAGE_LOAD(c1b)                                                         \
    _Pragma("unroll")                                                           \
    for (int i = 0; i < 10; ++i) {                                              \
        int q = i * 256 + t;                                                    \
        if (q < 2352) {                                                         \
            int ar = q >= 1176; int q2 = q - ar * 1176;                         \
            int pxi = q2 >> 2, cq = q2 & 3;                                     \
            int r = pxi / 98, wp = pxi - r * 98;                                \
            const unsigned short* src = ar ? xl : xh;                           \
            sreg[i] = *(const uint4*)(src + xrow0 + (size_t)(r * WP_ + wp) * C1_\
                                      + (c1b) * 32 + cq * 8);                   \
        }                                                                       \
    }
#define STAGE_WRITE()                                                           \
    _Pragma("unroll")                                                           \
    for (int i = 0; i < 10; ++i) {                                              \
        int q = i * 256 + t;                                                    \
        if (q < 2352) {                                                         \
            int ar = q >= 1176; int q2 = q - ar * 1176;                         \
            int pxi = q2 >> 2, cq = q2 & 3;                                     \
            int r = pxi / 98, wp = pxi - r * 98;                                \
            unsigned short* dst = ar ? Bl : Bh;                                 \
            int slot = (r * 98 + wp) * 4 + (cq ^ ((wp >> 1) & 3));              \
            *(uint4*)(dst + slot * 8) = sreg[i];                                \
        }                                                                       \
    }

    STAGE_LOAD(0);
#pragma unroll 1
    for (int c1b = 0; c1b < 4; ++c1b) {
        __syncthreads();                        // LDS free of previous reads
        STAGE_WRITE();
        __syncthreads();
        if (c1b < 3) { STAGE_LOAD(c1b + 1); }   // in flight during MFMAs
#pragma unroll
        for (int j = 0; j < 9; ++j) {
            const int ky = j / 3, kx = j % 3;
            bf16x8 ah[4], al[4], bh[3], bl[3];
            const size_t abase =
                ((((size_t)(b * 9 + j) * 4 + c1b) * 8 + wm * 4) * 64 + lane) * 8;
#pragma unroll
            for (int m = 0; m < 4; ++m) {
                ah[m] = *(const bf16x8*)(whf + abase + (size_t)m * 512);
                al[m] = *(const bf16x8*)(wlf + abase + (size_t)m * 512);
            }
#pragma unroll
            for (int n = 0; n < 3; ++n) {
                const int wp = wn * 48 + n * 16 + l15 + kx;
                const int slot = (ky * 98 + wp) * 4 + (koct ^ ((wp >> 1) & 3));
                bh[n] = *(const bf16x8*)(Bh + slot * 8);
                bl[n] = *(const bf16x8*)(Bl + slot * 8);
            }
#pragma unroll
            for (int m = 0; m < 4; ++m)
#pragma unroll
                for (int n = 0; n < 3; ++n) {
                    acc[m][n] = __builtin_amdgcn_mfma_f32_16x16x32_bf16(
                        ah[m], bh[n], acc[m][n], 0, 0, 0);
                    acc[m][n] = __builtin_amdgcn_mfma_f32_16x16x32_bf16(
                        al[m], bh[n], acc[m][n], 0, 0, 0);
                    acc[m][n] = __builtin_amdgcn_mfma_f32_16x16x32_bf16(
                        ah[m], bl[n], acc[m][n], 0, 0, 0);
                }
        }
    }
    // epilogue: + bias, store y fp32. C/D: col=lane&15, row=(lane>>4)*4+reg.
#pragma unroll
    for (int m = 0; m < 4; ++m) {
        const int c2b = wm * 64 + m * 16 + koct * 4;
        float bv[4];
#pragma unroll
        for (int r = 0; r < 4; ++r) bv[r] = bmix[b * C2_ + c2b + r];
#pragma unroll
        for (int n = 0; n < 3; ++n) {
            const int w = wn * 48 + n * 16 + l15;
#pragma unroll
            for (int r = 0; r < 4; ++r)
                y[((size_t)(b * C2_ + c2b + r)) * HW_ + h * W_ + w] = acc[m][n][r] + bv[r];
        }
    }
#undef STAGE_LOAD
#undef STAGE_WRITE
}

__device__ inline float wave_reduce_sum(float v) {
#pragma unroll
    for (int o = 32; o > 0; o >>= 1) v += __shfl_down(v, o, 64);
    return v;
}

// ---------------- BN partial stats ----------------
__global__ __launch_bounds__(256) void k_bnstat(const float* __restrict__ y,
                                                float* __restrict__ psum,
                                                float* __restrict__ psq) {
    const int c2 = blockIdx.x, s = blockIdx.y, t = threadIdx.x;
    float sum = 0.f, sq = 0.f;
#pragma unroll
    for (int bi = 0; bi < 4; ++bi) {
        const int b = s * 4 + bi;
        const float4* p = (const float4*)(y + ((size_t)(b * C2_ + c2)) * HW_);
#pragma unroll
        for (int i = 0; i < 9; ++i) {
            float4 v = p[t + i * 256];
            sum += v.x + v.y + v.z + v.w;
            sq  += v.x * v.x + v.y * v.y + v.z * v.z + v.w * v.w;
        }
    }
    sum = wave_reduce_sum(sum);
    sq  = wave_reduce_sum(sq);
    __shared__ float ls[2][4];
    if ((t & 63) == 0) { ls[0][t >> 6] = sum; ls[1][t >> 6] = sq; }
    __syncthreads();
    if (t == 0) {
        psum[c2 * 8 + s] = ls[0][0] + ls[0][1] + ls[0][2] + ls[0][3];
        psq [c2 * 8 + s] = ls[1][0] + ls[1][1] + ls[1][2] + ls[1][3];
    }
}

__global__ __launch_bounds__(128) void k_bnfinal(const float* __restrict__ psum,
                                                 const float* __restrict__ psq,
                                                 const float* __restrict__ gamma,
                                                 const float* __restrict__ beta,
                                                 float* __restrict__ scale,
                                                 float* __restrict__ shift) {
    const int c2 = threadIdx.x;
    float s = 0.f, q = 0.f;
#pragma unroll
    for (int i = 0; i < 8; ++i) { s += psum[c2 * 8 + i]; q += psq[c2 * 8 + i]; }
    const float n = (float)(B_ * HW_);
    const float mean = s / n;
    const float var  = q / n - mean * mean;
    const float sc   = gamma[c2] * rsqrtf(var + EPS_);
    scale[c2] = sc;
    shift[c2] = beta[c2] - mean * sc;
}

__global__ __launch_bounds__(256) void k_silu(float* __restrict__ y,
                                              const float* __restrict__ scale,
                                              const float* __restrict__ shift) {
    const int bc = blockIdx.y;
    const int c2 = bc & 127;
    const int i  = blockIdx.x * 256 + threadIdx.x;
    const float sc = scale[c2], sh = shift[c2];
    float4* p = (float4*)(y + (size_t)bc * HW_);
    float4 v = p[i];
    float t0 = v.x * sc + sh; v.x = t0 / (1.f + __expf(-t0));
    float t1 = v.y * sc + sh; v.y = t1 / (1.f + __expf(-t1));
    float t2 = v.z * sc + sh; v.z = t2 / (1.f + __expf(-t2));
    float t3 = v.w * sc + sh; v.w = t3 / (1.f + __expf(-t3));
    p[i] = v;
}

extern "C" void kernel_launch(void* const* d_in, const int* in_sizes, int n_in,
                              void* d_out, int out_size, void* d_ws, size_t ws_size,
                              hipStream_t stream) {
    (void)in_sizes; (void)n_in; (void)out_size; (void)ws_size;
    const float* x      = (const float*)d_in[0];
    const float* fc_w   = (const float*)d_in[1];
    const float* fc_b   = (const float*)d_in[2];
    const float* weight = (const float*)d_in[3];
    const float* bias   = (const float*)d_in[4];
    const float* gamma  = (const float*)d_in[5];
    const float* beta   = (const float*)d_in[6];
    float* out = (float*)d_out;
    float* ws  = (float*)d_ws;

    float* gap   = ws + WS_GAP;
    float* gate  = ws + WS_GATE;
    float* bmix  = ws + WS_BMIX;
    float* psum  = ws + WS_PSUM;
    float* psq   = ws + WS_PSQ;
    float* scale = ws + WS_SCALE;
    float* shift = ws + WS_SHIFT;
    unsigned short* whf = (unsigned short*)(ws + WS_WHF);
    unsigned short* wlf = (unsigned short*)(ws + WS_WLF);
    unsigned short* xh  = (unsigned short*)(ws + WS_XH);
    unsigned short* xl  = (unsigned short*)(ws + WS_XL);

    hipMemsetAsync(gap, 0, C1_ * B_ * sizeof(float), stream);
    hipLaunchKernelGGL(k_xpad,   dim3(HP_, B_),   dim3(256), 0, stream, x, xh, xl, gap);
    hipLaunchKernelGGL(k_gate,   dim3(1),         dim3(128), 0, stream, gap, fc_w, fc_b, bias, gate, bmix);
    hipLaunchKernelGGL(k_wmixA,  dim3(36, B_),    dim3(256), 0, stream, weight, gate, whf, wlf);
    hipLaunchKernelGGL(k_conv,   dim3(H_, B_),    dim3(256), 0, stream, xh, xl, whf, wlf, bmix, out);
    hipLaunchKernelGGL(k_bnstat, dim3(C2_, 8),    dim3(256), 0, stream, out, psum, psq);
    hipLaunchKernelGGL(k_bnfinal,dim3(1),         dim3(128), 0, stream, psum, psq, gamma, beta, scale, shift);
    hipLaunchKernelGGL(k_silu,   dim3(9, B_ * C2_), dim3(256), 0, stream, out, scale, shift);
}

// Round 5
// 765.017 us; speedup vs baseline: 1.6282x; 1.2838x over previous
//
#include <hip/hip_runtime.h>
#include <cstdint>

// DynamicConv on MI355X — round 5 (= round 4 resubmit; r4 was an acquisition
// timeout, kernel never ran). Kill the sreg spill via global_load_lds.
// Round-3 post-mortem: WRITE_SIZE 595MB (y=147MB) + FETCH 740MB + VGPR=100 <
// live-state 144 => compiler spilled sreg[10] staging regs to scratch; the
// scratch round-trip per c1b was the 75% stall (MFMA ideal is ~33us, ran 443).
// Fix: direct global->LDS DMA (linear LDS dest, swizzle moved to SOURCE addr,
// same involution => read addressing unchanged). Plus __launch_bounds__(256,4),
// XCD-bijective block remap (each XCD owns 4 samples), float4 loads in k_xpad.
// Tripwire: if k_conv WRITE_SIZE stays >300MB, spill persists -> (256,3) next.

#define B_    32
#define C1_   128
#define C2_   128
#define H_    96
#define W_    96
#define HW_   (H_ * W_)
#define HP_   98
#define WP_   98
#define EPS_  1e-5f

typedef __attribute__((ext_vector_type(8))) __bf16 bf16x8;
typedef __attribute__((ext_vector_type(4))) float f32x4;

// ws layout in float slots:
#define WS_GAP   0
#define WS_GATE  4096
#define WS_BMIX  4224
#define WS_PSUM  8320
#define WS_PSQ   9344
#define WS_SCALE 10368
#define WS_SHIFT 10496
#define WS_WHF   10752                    // ushort[32*9*4*8*64*8]
#define WS_WLF   (WS_WHF + 2359296)
#define WS_XH    (WS_WLF + 2359296)       // ushort[32*98*98*128]
#define WS_XL    (WS_XH + 19668992)
// end = 44,067,328 floats = 176.3 MB

__device__ __forceinline__ void gl_lds16(const void* g, void* l) {
    __builtin_amdgcn_global_load_lds(
        (const __attribute__((address_space(1))) unsigned int*)g,
        (__attribute__((address_space(3))) unsigned int*)l, 16, 0, 0);
}

__device__ inline float bfbits2f(unsigned short u) {
    return (float)__builtin_bit_cast(__bf16, u);
}
__device__ inline unsigned short f2bfbits(__bf16 v) {
    return __builtin_bit_cast(unsigned short, v);
}

// ---------------- x -> padded NHWC bf16 hi/lo, + GAP sums ----------------
__global__ __launch_bounds__(256) void k_xpad(const float* __restrict__ x,
                                              unsigned short* __restrict__ xh,
                                              unsigned short* __restrict__ xl,
                                              float* __restrict__ gap) {
    __shared__ unsigned int lds[96 * 129];      // [w][c1]
    const int hp = blockIdx.x, b = blockIdx.y, t = threadIdx.x;
    const size_t rowbase = ((size_t)b * HP_ + hp) * WP_ * C1_;
    if (hp == 0 || hp == HP_ - 1) {             // zero pad rows
        const ushort4 z = {0, 0, 0, 0};
        for (int i = 0; i < 13; ++i) {
            int idx = i * 256 + t;
            if (idx < 3136) {
                *(ushort4*)(xh + rowbase + (size_t)idx * 4) = z;
                *(ushort4*)(xl + rowbase + (size_t)idx * 4) = z;
            }
        }
        return;
    }
    const int h = hp - 1;
    // phase 1: float4 reads of x rows, split to bf16 hi/lo packed in LDS
    for (int i = 0; i < 12; ++i) {
        int idx4 = i * 256 + t;                 // 0..3071 = c1*24 + w4
        int c1 = idx4 / 24, w4 = idx4 - c1 * 24;
        float4 v = *(const float4*)(x + ((size_t)(b * C1_ + c1)) * HW_ + h * W_ + w4 * 4);
        float fv[4] = {v.x, v.y, v.z, v.w};
#pragma unroll
        for (int e = 0; e < 4; ++e) {
            float f = fv[e];
            __bf16 hi = (__bf16)f;
            __bf16 lo = (__bf16)(f - (float)hi);
            lds[(w4 * 4 + e) * 129 + c1] =
                (unsigned int)f2bfbits(hi) | ((unsigned int)f2bfbits(lo) << 16);
        }
    }
    // w pads for this row
    if (t < 128) { xh[rowbase + t] = 0; xl[rowbase + t] = 0; }
    else {
        int c1 = t - 128;
        xh[rowbase + (size_t)(WP_ - 1) * C1_ + c1] = 0;
        xl[rowbase + (size_t)(WP_ - 1) * C1_ + c1] = 0;
    }
    __syncthreads();
    // phase 2: transposed NHWC write + GAP partials
    const int c14 = (t & 31) << 2;
    float s0 = 0, s1 = 0, s2 = 0, s3 = 0;
    for (int i = 0; i < 12; ++i) {
        int quad = i * 256 + t;                 // 0..3071
        int w = quad >> 5;
        unsigned int u0 = lds[w * 129 + c14 + 0];
        unsigned int u1 = lds[w * 129 + c14 + 1];
        unsigned int u2 = lds[w * 129 + c14 + 2];
        unsigned int u3 = lds[w * 129 + c14 + 3];
        ushort4 hv = {(unsigned short)u0, (unsigned short)u1,
                      (unsigned short)u2, (unsigned short)u3};
        ushort4 lv = {(unsigned short)(u0 >> 16), (unsigned short)(u1 >> 16),
                      (unsigned short)(u2 >> 16), (unsigned short)(u3 >> 16)};
        size_t off = rowbase + (size_t)(w + 1) * C1_ + c14;
        *(ushort4*)(xh + off) = hv;
        *(ushort4*)(xl + off) = lv;
        s0 += bfbits2f(hv.x) + bfbits2f(lv.x);
        s1 += bfbits2f(hv.y) + bfbits2f(lv.y);
        s2 += bfbits2f(hv.z) + bfbits2f(lv.z);
        s3 += bfbits2f(hv.w) + bfbits2f(lv.w);
    }
    s0 += __shfl_xor(s0, 32); s1 += __shfl_xor(s1, 32);
    s2 += __shfl_xor(s2, 32); s3 += __shfl_xor(s3, 32);
    if ((t & 63) < 32) {
        atomicAdd(&gap[b * C1_ + c14 + 0], s0);
        atomicAdd(&gap[b * C1_ + c14 + 1], s1);
        atomicAdd(&gap[b * C1_ + c14 + 2], s2);
        atomicAdd(&gap[b * C1_ + c14 + 3], s3);
    }
}

// ---------------- gating softmax + bmix (gap holds SUMS) ----------------
__global__ __launch_bounds__(128) void k_gate(const float* __restrict__ gap,
                                              const float* __restrict__ fc_w,
                                              const float* __restrict__ fc_b,
                                              const float* __restrict__ bias,
                                              float* __restrict__ gate,
                                              float* __restrict__ bmix) {
    const int t = threadIdx.x;
    if (t < B_) {
        const int b = t;
        const float inv = 1.0f / (float)HW_;
        float lg[4];
#pragma unroll
        for (int k = 0; k < 4; ++k) {
            float s = 0.f;
            for (int c = 0; c < C1_; ++c) s += gap[b * C1_ + c] * fc_w[k * C1_ + c];
            lg[k] = s * inv + fc_b[k];
        }
        float m = fmaxf(fmaxf(lg[0], lg[1]), fmaxf(lg[2], lg[3]));
        float e0 = __expf(lg[0] - m), e1 = __expf(lg[1] - m);
        float e2 = __expf(lg[2] - m), e3 = __expf(lg[3] - m);
        float inv2 = 1.f / (e0 + e1 + e2 + e3);
        gate[b * 4 + 0] = e0 * inv2; gate[b * 4 + 1] = e1 * inv2;
        gate[b * 4 + 2] = e2 * inv2; gate[b * 4 + 3] = e3 * inv2;
    }
    __syncthreads();
    const int c2 = t;
    for (int b = 0; b < B_; ++b) {
        float s = 0.f;
#pragma unroll
        for (int k = 0; k < 4; ++k) s += gate[b * 4 + k] * bias[k * C2_ + c2];
        bmix[b * C2_ + c2] = s;
    }
}

// ---------------- mixed weights -> fragment-ordered bf16 hi/lo ----------------
__global__ __launch_bounds__(256) void k_wmixA(const float* __restrict__ weight,
                                               const float* __restrict__ gate,
                                               unsigned short* __restrict__ whf,
                                               unsigned short* __restrict__ wlf) {
    const int jc = blockIdx.x;                  // j*4 + c1b
    const int j = jc >> 2, c1b = jc & 3;
    const int b = blockIdx.y, t = threadIdx.x;
    const int lane = t & 63, quarter = t >> 6;
    const int l15 = lane & 15, koct = lane >> 4;
    const float g0 = gate[b * 4 + 0], g1 = gate[b * 4 + 1];
    const float g2 = gate[b * 4 + 2], g3 = gate[b * 4 + 3];
#pragma unroll
    for (int gg = 0; gg < 2; ++gg) {
        const int g16 = quarter * 2 + gg;
        const int c2 = g16 * 16 + l15;
        unsigned int hw_[4], lw_[4];
#pragma unroll
        for (int ep = 0; ep < 4; ++ep) {
            unsigned short hv[2], lv[2];
#pragma unroll
            for (int s = 0; s < 2; ++s) {
                const int e = ep * 2 + s;
                const int c1 = c1b * 32 + koct * 8 + e;
                const size_t wi = ((size_t)c2 * C1_ + c1) * 9 + j;
                float mix = g0 * weight[wi] + g1 * weight[wi + 147456]
                          + g2 * weight[wi + 2 * 147456] + g3 * weight[wi + 3 * 147456];
                __bf16 hi = (__bf16)mix;
                __bf16 lo = (__bf16)(mix - (float)hi);
                hv[s] = f2bfbits(hi);
                lv[s] = f2bfbits(lo);
            }
            hw_[ep] = (unsigned int)hv[0] | ((unsigned int)hv[1] << 16);
            lw_[ep] = (unsigned int)lv[0] | ((unsigned int)lv[1] << 16);
        }
        const size_t base = ((((size_t)(b * 9 + j) * 4 + c1b) * 8 + g16) * 64 + lane) * 8;
        uint4 hu = {hw_[0], hw_[1], hw_[2], hw_[3]};
        uint4 lu = {lw_[0], lw_[1], lw_[2], lw_[3]};
        *(uint4*)(whf + base) = hu;
        *(uint4*)(wlf + base) = lu;
    }
}

// ---------------- MFMA implicit-GEMM conv ----------------
// Block 256 thr = 4 waves (2M x 2N); tile M=128(c2) x N=96(w); K=9*128 (x3
// split products). B-tile staged per c1-block via global_load_lds into ONE
// contiguous LDS array (linear dest; XOR swizzle applied to the SOURCE addr,
// same involution as round 3 => read addressing unchanged, 0 bank conflicts).
__global__ __launch_bounds__(256, 4) void k_conv(const unsigned short* __restrict__ xh,
                                                 const unsigned short* __restrict__ xl,
                                                 const unsigned short* __restrict__ whf,
                                                 const unsigned short* __restrict__ wlf,
                                                 const float* __restrict__ bmix,
                                                 float* __restrict__ y) {
    // [0..1176): Bh chunks, [1176..2352): Bl chunks; chunk = 16B = 8 ushorts
    __shared__ unsigned short BhBl[2352 * 8];
    const int t = threadIdx.x;
    // XCD-bijective remap: XCD k owns samples [4k,4k+4), h raster within
    const int flat = blockIdx.y * 96 + blockIdx.x;   // dispatch-linear id
    const int nf   = (flat & 7) * 384 + (flat >> 3);
    const int b    = nf / 96, h = nf - (nf / 96) * 96;
    const int wv = t >> 6, lane = t & 63;
    const int wm = wv >> 1, wn = wv & 1;
    const int l15 = lane & 15, koct = lane >> 4;
    const size_t xrow0 = ((size_t)b * HP_ + h) * WP_ * (size_t)C1_;

    f32x4 acc[4][3];
#pragma unroll
    for (int m = 0; m < 4; ++m)
#pragma unroll
        for (int n = 0; n < 3; ++n) acc[m][n] = (f32x4){0.f, 0.f, 0.f, 0.f};

#pragma unroll 1
    for (int c1b = 0; c1b < 4; ++c1b) {
        __syncthreads();                        // prior reads of BhBl complete
#pragma unroll
        for (int i = 0; i < 10; ++i) {          // 2352 chunks: 16B DMA each
            int q = i * 256 + t;
            if (q < 2352) {
                int ar = q >= 1176; int q2 = q - ar * 1176;
                int pxi = q2 >> 2, cq = q2 & 3;
                int r = pxi / 98, wp = pxi - r * 98;
                int cqs = cq ^ ((wp >> 1) & 3);          // swizzle on SOURCE
                const unsigned short* src = (ar ? xl : xh) + xrow0
                    + (size_t)(r * WP_ + wp) * C1_ + c1b * 32 + cqs * 8;
                gl_lds16(src, BhBl + (size_t)q * 8);     // linear LDS dest
            }
        }
        asm volatile("s_waitcnt vmcnt(0)" ::: "memory");
        __syncthreads();
#pragma unroll
        for (int j = 0; j < 9; ++j) {
            const int ky = j / 3, kx = j % 3;
            bf16x8 ah[4], al[4], bh[3], bl[3];
            const size_t abase =
                ((((size_t)(b * 9 + j) * 4 + c1b) * 8 + wm * 4) * 64 + lane) * 8;
#pragma unroll
            for (int m = 0; m < 4; ++m) {
                ah[m] = *(const bf16x8*)(whf + abase + (size_t)m * 512);
                al[m] = *(const bf16x8*)(wlf + abase + (size_t)m * 512);
            }
#pragma unroll
            for (int n = 0; n < 3; ++n) {
                const int wp = wn * 48 + n * 16 + l15 + kx;
                const int slot = (ky * 98 + wp) * 4 + (koct ^ ((wp >> 1) & 3));
                bh[n] = *(const bf16x8*)(BhBl + slot * 8);
                bl[n] = *(const bf16x8*)(BhBl + 9408 + slot * 8);
            }
#pragma unroll
            for (int m = 0; m < 4; ++m)
#pragma unroll
                for (int n = 0; n < 3; ++n) {
                    acc[m][n] = __builtin_amdgcn_mfma_f32_16x16x32_bf16(
                        ah[m], bh[n], acc[m][n], 0, 0, 0);
                    acc[m][n] = __builtin_amdgcn_mfma_f32_16x16x32_bf16(
                        al[m], bh[n], acc[m][n], 0, 0, 0);
                    acc[m][n] = __builtin_amdgcn_mfma_f32_16x16x32_bf16(
                        ah[m], bl[n], acc[m][n], 0, 0, 0);
                }
        }
    }
    // epilogue: + bias. C/D: col=lane&15, row=(lane>>4)*4+reg.
#pragma unroll
    for (int m = 0; m < 4; ++m) {
        const int c2b = wm * 64 + m * 16 + koct * 4;
        float bv[4];
#pragma unroll
        for (int r = 0; r < 4; ++r) bv[r] = bmix[b * C2_ + c2b + r];
#pragma unroll
        for (int n = 0; n < 3; ++n) {
            const int w = wn * 48 + n * 16 + l15;
#pragma unroll
            for (int r = 0; r < 4; ++r)
                y[((size_t)(b * C2_ + c2b + r)) * HW_ + h * W_ + w] = acc[m][n][r] + bv[r];
        }
    }
}

__device__ inline float wave_reduce_sum(float v) {
#pragma unroll
    for (int o = 32; o > 0; o >>= 1) v += __shfl_down(v, o, 64);
    return v;
}

// ---------------- BN partial stats ----------------
__global__ __launch_bounds__(256) void k_bnstat(const float* __restrict__ y,
                                                float* __restrict__ psum,
                                                float* __restrict__ psq) {
    const int c2 = blockIdx.x, s = blockIdx.y, t = threadIdx.x;
    float sum = 0.f, sq = 0.f;
#pragma unroll
    for (int bi = 0; bi < 4; ++bi) {
        const int b = s * 4 + bi;
        const float4* p = (const float4*)(y + ((size_t)(b * C2_ + c2)) * HW_);
#pragma unroll
        for (int i = 0; i < 9; ++i) {
            float4 v = p[t + i * 256];
            sum += v.x + v.y + v.z + v.w;
            sq  += v.x * v.x + v.y * v.y + v.z * v.z + v.w * v.w;
        }
    }
    sum = wave_reduce_sum(sum);
    sq  = wave_reduce_sum(sq);
    __shared__ float ls[2][4];
    if ((t & 63) == 0) { ls[0][t >> 6] = sum; ls[1][t >> 6] = sq; }
    __syncthreads();
    if (t == 0) {
        psum[c2 * 8 + s] = ls[0][0] + ls[0][1] + ls[0][2] + ls[0][3];
        psq [c2 * 8 + s] = ls[1][0] + ls[1][1] + ls[1][2] + ls[1][3];
    }
}

__global__ __launch_bounds__(128) void k_bnfinal(const float* __restrict__ psum,
                                                 const float* __restrict__ psq,
                                                 const float* __restrict__ gamma,
                                                 const float* __restrict__ beta,
                                                 float* __restrict__ scale,
                                                 float* __restrict__ shift) {
    const int c2 = threadIdx.x;
    float s = 0.f, q = 0.f;
#pragma unroll
    for (int i = 0; i < 8; ++i) { s += psum[c2 * 8 + i]; q += psq[c2 * 8 + i]; }
    const float n = (float)(B_ * HW_);
    const float mean = s / n;
    const float var  = q / n - mean * mean;
    const float sc   = gamma[c2] * rsqrtf(var + EPS_);
    scale[c2] = sc;
    shift[c2] = beta[c2] - mean * sc;
}

__global__ __launch_bounds__(256) void k_silu(float* __restrict__ y,
                                              const float* __restrict__ scale,
                                              const float* __restrict__ shift) {
    const int bc = blockIdx.y;
    const int c2 = bc & 127;
    const int i  = blockIdx.x * 256 + threadIdx.x;
    const float sc = scale[c2], sh = shift[c2];
    float4* p = (float4*)(y + (size_t)bc * HW_);
    float4 v = p[i];
    float t0 = v.x * sc + sh; v.x = t0 / (1.f + __expf(-t0));
    float t1 = v.y * sc + sh; v.y = t1 / (1.f + __expf(-t1));
    float t2 = v.z * sc + sh; v.z = t2 / (1.f + __expf(-t2));
    float t3 = v.w * sc + sh; v.w = t3 / (1.f + __expf(-t3));
    p[i] = v;
}

extern "C" void kernel_launch(void* const* d_in, const int* in_sizes, int n_in,
                              void* d_out, int out_size, void* d_ws, size_t ws_size,
                              hipStream_t stream) {
    (void)in_sizes; (void)n_in; (void)out_size; (void)ws_size;
    const float* x      = (const float*)d_in[0];
    const float* fc_w   = (const float*)d_in[1];
    const float* fc_b   = (const float*)d_in[2];
    const float* weight = (const float*)d_in[3];
    const float* bias   = (const float*)d_in[4];
    const float* gamma  = (const float*)d_in[5];
    const float* beta   = (const float*)d_in[6];
    float* out = (float*)d_out;
    float* ws  = (float*)d_ws;

    float* gap   = ws + WS_GAP;
    float* gate  = ws + WS_GATE;
    float* bmix  = ws + WS_BMIX;
    float* psum  = ws + WS_PSUM;
    float* psq   = ws + WS_PSQ;
    float* scale = ws + WS_SCALE;
    float* shift = ws + WS_SHIFT;
    unsigned short* whf = (unsigned short*)(ws + WS_WHF);
    unsigned short* wlf = (unsigned short*)(ws + WS_WLF);
    unsigned short* xh  = (unsigned short*)(ws + WS_XH);
    unsigned short* xl  = (unsigned short*)(ws + WS_XL);

    hipMemsetAsync(gap, 0, C1_ * B_ * sizeof(float), stream);
    hipLaunchKernelGGL(k_xpad,   dim3(HP_, B_),   dim3(256), 0, stream, x, xh, xl, gap);
    hipLaunchKernelGGL(k_gate,   dim3(1),         dim3(128), 0, stream, gap, fc_w, fc_b, bias, gate, bmix);
    hipLaunchKernelGGL(k_wmixA,  dim3(36, B_),    dim3(256), 0, stream, weight, gate, whf, wlf);
    hipLaunchKernelGGL(k_conv,   dim3(96, B_),    dim3(256), 0, stream, xh, xl, whf, wlf, bmix, out);
    hipLaunchKernelGGL(k_bnstat, dim3(C2_, 8),    dim3(256), 0, stream, out, psum, psq);
    hipLaunchKernelGGL(k_bnfinal,dim3(1),         dim3(128), 0, stream, psum, psq, gamma, beta, scale, shift);
    hipLaunchKernelGGL(k_silu,   dim3(9, B_ * C2_), dim3(256), 0, stream, out, scale, shift);
}